// Round 12
// baseline (196.527 us; speedup 1.0000x reference)
//
#include <hip/hip_runtime.h>
#include <math.h>

// MLA decode attention, flash-decoding split + bf16 MFMA core.
// B=64, H=16, latent D=576, V=512, MAX_LEN=4096. fp32 in/out.
//
// R11 changes vs R10 (145.6us):
//  1) kc-SPLIT SCORES: the 4 waves no longer redundantly compute the same
//     S[16,32] (144 MFMA + 144 ds_read_b128 per block-round). Wave w now
//     computes partial scores over kc range {0-4,5-9,10-13,14-17} only
//     (10/10/8/8 MFMAs), writes f32 partials into an 8KB exchange buffer
//     ALIASED INTO K_s (dead between the post-score barrier and the next
//     STAGE_WRITE), and each wave sums all 4 partials. Block-round MFMAs
//     176->68, K_s b128 reads 144->36 (+8 writes/24 reads exchange,
//     +2 barriers). Q-frags per wave shrink 18->5 (-52 VGPR).
//  2) staging guarded at `end`: no fetch of rows past the chunk (was ~10%
//     of FETCH + a latent OOB read past the cache for batch 63).
//  3) mla_reduce: 4x-unrolled max pass, 2x-unrolled merge pass (the serial
//     dependent-load loops were ~5-15us).
//  Unchanged from R10: T14 async stage (issue-early/write-late), dual-write
//  K_s row-major + Vt transposed, log2-domain softmax, P_s transpose, PV 8
//  mfma/wave over private 128 v-cols, LDS 79360B -> 2 blocks/CU.

typedef __attribute__((ext_vector_type(8))) short bf16x8;
typedef __attribute__((ext_vector_type(4))) float f32x4;

namespace {
constexpr int NB = 64, NH = 16, MAXLEN = 4096, D = 576, DV = 512;
constexpr int KP = 584;   // K_s row stride (bf16): 1168 B rows, 16B-aligned
constexpr int VP = 36;    // Vt row stride (bf16): 72 B rows, 8B-aligned
constexpr int PP = 40;    // P_s row stride (bf16)
constexpr float SCALE_LOG2E = 0.041666666666666664f * 1.4426950408889634f;
constexpr float NEGINF = -1e30f;
}

__device__ __forceinline__ uint32_t cvtpk(float a, float b) {
    uint32_t r;
    asm("v_cvt_pk_bf16_f32 %0, %1, %2" : "=v"(r) : "v"(a), "v"(b));
    return r;   // low16 = bf16(a), high16 = bf16(b)
}

union FragAB { bf16x8 v; uint32_t u[4]; };

__global__ __launch_bounds__(256, 2)
void mla_mfma(const float* __restrict__ qg, const float* __restrict__ kvnew,
              const float* __restrict__ cache, const int* __restrict__ lens,
              float* __restrict__ ws_o, float* __restrict__ ws_ml,
              int nchunk, int chunk)
{
    const int c = blockIdx.x, b = blockIdx.y;
    const int total = lens[b] + 1;
    const int start = c * chunk;
    if (start >= total) return;               // uniform, before any barrier
    const int end = min(start + chunk, total);
    const int newpos = total - 1;

    __shared__ __align__(16) short K_s[32 * KP];   // 37376 B (Sp aliases 8KB)
    __shared__ short V_s[DV * VP];                 // 36864 B Vt[v][r]
    __shared__ short P_s[4 * 16 * PP];             //  5120 B (total 79360)

    const int tid  = (int)threadIdx.x;
    const int wave = tid >> 6, lane = tid & 63;
    const int lr = lane & 15, g = lane >> 4;

    const float* vnew = kvnew + (size_t)b * D;
    const float* cb   = cache + (size_t)b * MAXLEN * D;

    const int rg = tid >> 5;                  // staging row-group: rows rg*4+i
    const int cl = tid & 31;                  // staging col-lane

    // kc partition per wave: {0-4, 5-9, 10-13, 14-17}
    const int kc0 = (wave < 2) ? 5 * wave : 4 * wave + 2;
    const int kcn = (wave < 2) ? 5 : 4;

    float4 nx[5][4] = {};                     // in-flight stage regs (zeroed)

    // STAGE_LOAD: issue next tile's global loads into nx (rows >= end skipped)
#define STAGE_LOAD(R0N)                                                        \
    {                                                                          \
        const int gr0 = (R0N) + rg * 4;                                        \
        const float* s0 = (gr0     == newpos) ? vnew : (cb + (size_t)(gr0    ) * D); \
        const float* s1 = (gr0 + 1 == newpos) ? vnew : (cb + (size_t)(gr0 + 1) * D); \
        const float* s2 = (gr0 + 2 == newpos) ? vnew : (cb + (size_t)(gr0 + 2) * D); \
        const float* s3 = (gr0 + 3 == newpos) ? vnew : (cb + (size_t)(gr0 + 3) * D); \
        _Pragma("unroll")                                                      \
        for (int it = 0; it < 5; ++it) {                                       \
            const int cf = 32 * it + cl;                                       \
            if (cf < 144) {                                                    \
                if (gr0     < end) nx[it][0] = *(const float4*)(s0 + cf * 4);  \
                if (gr0 + 1 < end) nx[it][1] = *(const float4*)(s1 + cf * 4);  \
                if (gr0 + 2 < end) nx[it][2] = *(const float4*)(s2 + cf * 4);  \
                if (gr0 + 3 < end) nx[it][3] = *(const float4*)(s3 + cf * 4);  \
            }                                                                  \
        }                                                                      \
    }

    // STAGE_WRITE: cvtpk nx -> K_s (row-major) + Vt (transposed)
#define STAGE_WRITE()                                                          \
    {                                                                          \
        _Pragma("unroll")                                                      \
        for (int it = 0; it < 5; ++it) {                                       \
            const int cf = 32 * it + cl;                                       \
            if (cf < 144) {                                                    \
                uint2 w;                                                       \
                w.x = cvtpk(nx[it][0].x, nx[it][0].y);                         \
                w.y = cvtpk(nx[it][0].z, nx[it][0].w);                         \
                *(uint2*)&K_s[(rg * 4 + 0) * KP + cf * 4] = w;                 \
                w.x = cvtpk(nx[it][1].x, nx[it][1].y);                         \
                w.y = cvtpk(nx[it][1].z, nx[it][1].w);                         \
                *(uint2*)&K_s[(rg * 4 + 1) * KP + cf * 4] = w;                 \
                w.x = cvtpk(nx[it][2].x, nx[it][2].y);                         \
                w.y = cvtpk(nx[it][2].z, nx[it][2].w);                         \
                *(uint2*)&K_s[(rg * 4 + 2) * KP + cf * 4] = w;                 \
                w.x = cvtpk(nx[it][3].x, nx[it][3].y);                         \
                w.y = cvtpk(nx[it][3].z, nx[it][3].w);                         \
                *(uint2*)&K_s[(rg * 4 + 3) * KP + cf * 4] = w;                 \
                if (cf < 128) {                                                \
                    const int v0 = cf * 4;                                     \
                    w.x = cvtpk(nx[it][0].x, nx[it][1].x);                     \
                    w.y = cvtpk(nx[it][2].x, nx[it][3].x);                     \
                    *(uint2*)&V_s[(v0 + 0) * VP + rg * 4] = w;                 \
                    w.x = cvtpk(nx[it][0].y, nx[it][1].y);                     \
                    w.y = cvtpk(nx[it][2].y, nx[it][3].y);                     \
                    *(uint2*)&V_s[(v0 + 1) * VP + rg * 4] = w;                 \
                    w.x = cvtpk(nx[it][0].z, nx[it][1].z);                     \
                    w.y = cvtpk(nx[it][2].z, nx[it][3].z);                     \
                    *(uint2*)&V_s[(v0 + 2) * VP + rg * 4] = w;                 \
                    w.x = cvtpk(nx[it][0].w, nx[it][1].w);                     \
                    w.y = cvtpk(nx[it][2].w, nx[it][3].w);                     \
                    *(uint2*)&V_s[(v0 + 3) * VP + rg * 4] = w;                 \
                }                                                              \
            }                                                                  \
        }                                                                      \
    }

    // ---- Q A-frags: ONLY this wave's kc range (5 frags max), scale folded --
    FragAB qf[5];
    {
        const float* qrow = qg + ((size_t)b * NH + lr) * D + g * 8;
        #pragma unroll
        for (int kcl = 0; kcl < 5; ++kcl) {
            if (kcl < kcn) {
                const float* qp = qrow + (kc0 + kcl) * 32;
                float4 x = *(const float4*)(qp);
                float4 y = *(const float4*)(qp + 4);
                qf[kcl].u[0] = cvtpk(x.x * SCALE_LOG2E, x.y * SCALE_LOG2E);
                qf[kcl].u[1] = cvtpk(x.z * SCALE_LOG2E, x.w * SCALE_LOG2E);
                qf[kcl].u[2] = cvtpk(y.x * SCALE_LOG2E, y.y * SCALE_LOG2E);
                qf[kcl].u[3] = cvtpk(y.z * SCALE_LOG2E, y.w * SCALE_LOG2E);
            }
        }
    }

    f32x4 acc[8];
    #pragma unroll
    for (int i = 0; i < 8; ++i) acc[i] = (f32x4){0.f, 0.f, 0.f, 0.f};
    float m2[4] = {NEGINF, NEGINF, NEGINF, NEGINF};
    float ll[4] = {0.f, 0.f, 0.f, 0.f};

    // ---- prologue: stage tile 0 (load -> write -> barrier) ----
    STAGE_LOAD(start);
    STAGE_WRITE();
    __syncthreads();

    for (int r0 = start; r0 < end; r0 += 32) {
        const bool have_next = (r0 + 32 < end);     // block-uniform
        if (have_next) STAGE_LOAD(r0 + 32);         // issue only; no waits

        // ---- partial scores over this wave's kc range ----
        f32x4 p0t = (f32x4){0.f, 0.f, 0.f, 0.f};
        f32x4 p1t = (f32x4){0.f, 0.f, 0.f, 0.f};
        #pragma unroll
        for (int kcl = 0; kcl < 5; ++kcl) {
            if (kcl < kcn) {                        // wave-uniform predicate
                const int ko = (kc0 + kcl) * 32 + g * 8;
                FragAB kb0, kb1;
                kb0.v = *(const bf16x8*)&K_s[lr * KP + ko];
                kb1.v = *(const bf16x8*)&K_s[(16 + lr) * KP + ko];
                p0t = __builtin_amdgcn_mfma_f32_16x16x32_bf16(qf[kcl].v, kb0.v, p0t, 0, 0, 0);
                p1t = __builtin_amdgcn_mfma_f32_16x16x32_bf16(qf[kcl].v, kb1.v, p1t, 0, 0, 0);
            }
        }
        __syncthreads();                  // all waves done reading K_s

        // ---- exchange partials through Sp (aliases K_s's first 8 KB) ----
        float* Sp = (float*)&K_s[0];
        *(f32x4*)&Sp[((wave * 2 + 0) * 64 + lane) * 4] = p0t;
        *(f32x4*)&Sp[((wave * 2 + 1) * 64 + lane) * 4] = p1t;
        __syncthreads();                  // partials visible

        f32x4 sc0 = p0t, sc1 = p1t;
        #pragma unroll
        for (int dw = 1; dw < 4; ++dw) {
            const int w2 = (wave + dw) & 3;
            sc0 += *(const f32x4*)&Sp[((w2 * 2 + 0) * 64 + lane) * 4];
            sc1 += *(const f32x4*)&Sp[((w2 * 2 + 1) * 64 + lane) * 4];
        }

        // mask invalid rows (lane's D-col = row r0+lr / r0+16+lr)
        if (r0 + lr >= end)      sc0 = (f32x4){NEGINF, NEGINF, NEGINF, NEGINF};
        if (r0 + 16 + lr >= end) sc1 = (f32x4){NEGINF, NEGINF, NEGINF, NEGINF};

        // ---- online softmax, 4 head-channels per lane (log2 domain) ----
        float p0[4], p1[4], scl[4];
        #pragma unroll
        for (int i = 0; i < 4; ++i) {
            float mt = fmaxf(sc0[i], sc1[i]);
            mt = fmaxf(mt, __shfl_xor(mt, 1));
            mt = fmaxf(mt, __shfl_xor(mt, 2));
            mt = fmaxf(mt, __shfl_xor(mt, 4));
            mt = fmaxf(mt, __shfl_xor(mt, 8));
            const float nm = fmaxf(m2[i], mt);
            scl[i] = exp2f(m2[i] - nm);
            p0[i] = exp2f(sc0[i] - nm);
            p1[i] = exp2f(sc1[i] - nm);
            float rs = p0[i] + p1[i];
            rs += __shfl_xor(rs, 1);
            rs += __shfl_xor(rs, 2);
            rs += __shfl_xor(rs, 4);
            rs += __shfl_xor(rs, 8);
            ll[i] = ll[i] * scl[i] + rs;
            m2[i] = nm;
        }

        // ---- P -> bf16, per-wave LDS transpose, re-read as PV A-frag ----
        short* pw = &P_s[wave * 16 * PP];
        #pragma unroll
        for (int i = 0; i < 4; ++i) {
            pw[(4 * g + i) * PP + lr]      = (short)cvtpk(p0[i], p0[i]);
            pw[(4 * g + i) * PP + 16 + lr] = (short)cvtpk(p1[i], p1[i]);
        }
        asm volatile("s_waitcnt lgkmcnt(0)" ::: "memory");  // cross-lane RAW
        FragAB pa;
        pa.v = *(const bf16x8*)&pw[lr * PP + g * 8];

        // ---- PV: wave's 128 v-cols, 8 mfma; rescale acc per head-chan ----
        const f32x4 scl4 = (f32x4){scl[0], scl[1], scl[2], scl[3]};
        #pragma unroll
        for (int vt = 0; vt < 8; ++vt) {
            const int v = wave * 128 + vt * 16 + lr;
            FragAB vb;
            *(uint2*)&vb.u[0] = *(const uint2*)&V_s[v * VP + g * 8];
            *(uint2*)&vb.u[2] = *(const uint2*)&V_s[v * VP + g * 8 + 4];
            acc[vt] = acc[vt] * scl4;
            acc[vt] = __builtin_amdgcn_mfma_f32_16x16x32_bf16(pa.v, vb.v, acc[vt], 0, 0, 0);
        }

        __syncthreads();                      // all waves done reading LDS
        if (have_next) STAGE_WRITE();         // waits on nx loads, writes LDS
        __syncthreads();                      // next round staged
    }

    // ---- write partials: lane covers h = 4g+i, v = wave*128 + vt*16 + lr --
    float* ob = ws_o + (((size_t)b * nchunk + c) * NH) * DV;
    #pragma unroll
    for (int vt = 0; vt < 8; ++vt) {
        const int v = wave * 128 + vt * 16 + lr;
        #pragma unroll
        for (int i = 0; i < 4; ++i)
            ob[(4 * g + i) * DV + v] = acc[vt][i];
    }
    if (wave == 0 && lr == 0) {
        float* mlb = ws_ml + ((size_t)b * nchunk + c) * NH * 2;
        #pragma unroll
        for (int i = 0; i < 4; ++i) {
            mlb[(4 * g + i) * 2]     = m2[i];   // log2-domain running max
            mlb[(4 * g + i) * 2 + 1] = ll[i];
        }
    }
#undef STAGE_LOAD
#undef STAGE_WRITE
}

__global__ __launch_bounds__(256)
void mla_reduce(const int* __restrict__ lens,
                const float* __restrict__ ws_o,
                const float* __restrict__ ws_ml,
                float* __restrict__ out,
                int nchunk, int chunk)
{
    const int h = blockIdx.x;
    const int b = blockIdx.y;
    const int tid = (int)threadIdx.x;
    const int total = lens[b] + 1;
    const int nact = min(nchunk, (total + chunk - 1) / chunk);

    float M = NEGINF;
    {
        int c = 0;
        for (; c + 4 <= nact; c += 4) {       // 4 independent loads in flight
            const float m0 = ws_ml[(((size_t)b * nchunk + c    ) * NH + h) * 2];
            const float m1 = ws_ml[(((size_t)b * nchunk + c + 1) * NH + h) * 2];
            const float m2_ = ws_ml[(((size_t)b * nchunk + c + 2) * NH + h) * 2];
            const float m3 = ws_ml[(((size_t)b * nchunk + c + 3) * NH + h) * 2];
            M = fmaxf(M, fmaxf(fmaxf(m0, m1), fmaxf(m2_, m3)));
        }
        for (; c < nact; ++c)
            M = fmaxf(M, ws_ml[(((size_t)b * nchunk + c) * NH + h) * 2]);
    }

    float a0 = 0.f, a1 = 0.f, L = 0.f;
    {
        int c = 0;
        for (; c + 2 <= nact; c += 2) {       // 2 independent iterations
            const size_t mlb0 = (((size_t)b * nchunk + c    ) * NH + h) * 2;
            const size_t mlb1 = (((size_t)b * nchunk + c + 1) * NH + h) * 2;
            const float w0 = exp2f(ws_ml[mlb0] - M);
            const float w1 = exp2f(ws_ml[mlb1] - M);
            const float2 o0 = *(const float2*)&ws_o[
                (((size_t)b * nchunk + c    ) * NH + h) * (size_t)DV + 2 * tid];
            const float2 o1 = *(const float2*)&ws_o[
                (((size_t)b * nchunk + c + 1) * NH + h) * (size_t)DV + 2 * tid];
            L += w0 * ws_ml[mlb0 + 1] + w1 * ws_ml[mlb1 + 1];
            a0 = fmaf(w1, o1.x, fmaf(w0, o0.x, a0));
            a1 = fmaf(w1, o1.y, fmaf(w0, o0.y, a1));
        }
        for (; c < nact; ++c) {
            const size_t mlb = (((size_t)b * nchunk + c) * NH + h) * 2;
            const float w = exp2f(ws_ml[mlb] - M);
            L += w * ws_ml[mlb + 1];
            const float2 o = *(const float2*)&ws_o[
                (((size_t)b * nchunk + c) * NH + h) * (size_t)DV + 2 * tid];
            a0 = fmaf(w, o.x, a0);
            a1 = fmaf(w, o.y, a1);
        }
    }
    const float inv = 1.f / L;
    *(float2*)&out[((size_t)b * NH + h) * (size_t)DV + 2 * tid] =
        make_float2(a0 * inv, a1 * inv);
}

extern "C" void kernel_launch(void* const* d_in, const int* in_sizes, int n_in,
                              void* d_out, int out_size, void* d_ws, size_t ws_size,
                              hipStream_t stream)
{
    (void)in_sizes; (void)n_in; (void)out_size;
    const float* qg    = (const float*)d_in[0];   // [B,H,576]
    const float* kvnew = (const float*)d_in[1];   // [B,1,576]
    const float* cache = (const float*)d_in[2];   // [B,4096,576]
    const int*   lens  = (const int*)d_in[3];     // [B]
    float* out = (float*)d_out;                   // [B,H,512] fp32

    // largest chunk split that fits the workspace (67 MB at nchunk=32)
    int nchunk = 32;
    while (nchunk > 1 &&
           (size_t)NB * nchunk * NH * (DV + 2) * sizeof(float) > ws_size)
        nchunk >>= 1;
    const int chunk = MAXLEN / nchunk;            // multiple of 32

    float* ws_o  = (float*)d_ws;
    float* ws_ml = ws_o + (size_t)NB * nchunk * NH * DV;

    dim3 gA(nchunk, NB);
    mla_mfma<<<gA, 256, 0, stream>>>(qg, kvnew, cache, lens, ws_o, ws_ml,
                                     nchunk, chunk);
    dim3 gB(NH, NB);
    mla_reduce<<<gB, 256, 0, stream>>>(lens, ws_o, ws_ml, out, nchunk, chunk);
}

// Round 13
// 143.694 us; speedup vs baseline: 1.3677x; 1.3677x over previous
//
#include <hip/hip_runtime.h>
#include <math.h>

// MLA decode attention, flash-decoding split + bf16 MFMA core.
// B=64, H=16, latent D=576, V=512, MAX_LEN=4096. fp32 in/out.
//
// R12 = R10 (145.6us, best verified) + low-risk fixes. R11's bundle
// (kc-split + 4 barriers/round + divergent load guards) regressed to 196us:
// redundant score MFMAs were free; barriers/divergence were not.
//  - R10 skeleton: T14 async stage (issue-early/write-late), dual-write
//    K_s row-major + Vt transposed, 4-wave redundant scores, log2 softmax,
//    P_s transpose, PV 8 mfma/wave, LDS 79360B -> 2 blocks/CU.
//  + branchless OOB fix: staged row index clamped to 4095 (R10 could read
//    past the cache tail for the last batch; garbage rows are masked).
//  + mla_reduce: 4x/2x unrolled passes (independent loads in flight).
//  + T5 s_setprio(1) around score and PV MFMA clusters.

typedef __attribute__((ext_vector_type(8))) short bf16x8;
typedef __attribute__((ext_vector_type(4))) float f32x4;

namespace {
constexpr int NB = 64, NH = 16, MAXLEN = 4096, D = 576, DV = 512;
constexpr int KP = 584;   // K_s row stride (bf16): 1168 B rows, 16B-aligned
constexpr int VP = 36;    // Vt row stride (bf16): 72 B rows, 8B-aligned
constexpr int PP = 40;    // P_s row stride (bf16)
constexpr float SCALE_LOG2E = 0.041666666666666664f * 1.4426950408889634f;
constexpr float NEGINF = -1e30f;
}

__device__ __forceinline__ uint32_t cvtpk(float a, float b) {
    uint32_t r;
    asm("v_cvt_pk_bf16_f32 %0, %1, %2" : "=v"(r) : "v"(a), "v"(b));
    return r;   // low16 = bf16(a), high16 = bf16(b)
}

union FragAB { bf16x8 v; uint32_t u[4]; };

__global__ __launch_bounds__(256, 2)
void mla_mfma(const float* __restrict__ qg, const float* __restrict__ kvnew,
              const float* __restrict__ cache, const int* __restrict__ lens,
              float* __restrict__ ws_o, float* __restrict__ ws_ml,
              int nchunk, int chunk)
{
    const int c = blockIdx.x, b = blockIdx.y;
    const int total = lens[b] + 1;
    const int start = c * chunk;
    if (start >= total) return;               // uniform, before any barrier
    const int end = min(start + chunk, total);
    const int newpos = total - 1;

    __shared__ short K_s[32 * KP];            // 37376 B row-major bf16
    __shared__ short V_s[DV * VP];            // 36864 B Vt[v][r] bf16
    __shared__ short P_s[4 * 16 * PP];        //  5120 B   (total 79360)

    const int tid  = (int)threadIdx.x;
    const int wave = tid >> 6, lane = tid & 63;
    const int lr = lane & 15, g = lane >> 4;

    const float* vnew = kvnew + (size_t)b * D;
    const float* cb   = cache + (size_t)b * MAXLEN * D;

    const int rg = tid >> 5;                  // staging row-group: rows rg*4+i
    const int cl = tid & 31;                  // staging col-lane

    float4 nx[5][4];                          // in-flight stage registers

    // STAGE_LOAD: issue next tile's loads into nx. Row index clamped to
    // MAXLEN-1 (branchless): rows past `end` are garbage but in-bounds and
    // masked downstream. newpos substitution unchanged.
#define STAGE_LOAD(R0N)                                                        \
    {                                                                          \
        const int gr0 = (R0N) + rg * 4;                                        \
        const int r0c = min(gr0,     MAXLEN - 1);                              \
        const int r1c = min(gr0 + 1, MAXLEN - 1);                              \
        const int r2c = min(gr0 + 2, MAXLEN - 1);                              \
        const int r3c = min(gr0 + 3, MAXLEN - 1);                              \
        const float* s0 = (gr0     == newpos) ? vnew : (cb + (size_t)r0c * D); \
        const float* s1 = (gr0 + 1 == newpos) ? vnew : (cb + (size_t)r1c * D); \
        const float* s2 = (gr0 + 2 == newpos) ? vnew : (cb + (size_t)r2c * D); \
        const float* s3 = (gr0 + 3 == newpos) ? vnew : (cb + (size_t)r3c * D); \
        _Pragma("unroll")                                                      \
        for (int it = 0; it < 5; ++it) {                                       \
            const int cf = 32 * it + cl;                                       \
            if (cf < 144) {                                                    \
                nx[it][0] = *(const float4*)(s0 + cf * 4);                     \
                nx[it][1] = *(const float4*)(s1 + cf * 4);                     \
                nx[it][2] = *(const float4*)(s2 + cf * 4);                     \
                nx[it][3] = *(const float4*)(s3 + cf * 4);                     \
            }                                                                  \
        }                                                                      \
    }

    // STAGE_WRITE: cvtpk nx -> K_s (row-major) + Vt (transposed)
#define STAGE_WRITE()                                                          \
    {                                                                          \
        _Pragma("unroll")                                                      \
        for (int it = 0; it < 5; ++it) {                                       \
            const int cf = 32 * it + cl;                                       \
            if (cf < 144) {                                                    \
                uint2 w;                                                       \
                w.x = cvtpk(nx[it][0].x, nx[it][0].y);                         \
                w.y = cvtpk(nx[it][0].z, nx[it][0].w);                         \
                *(uint2*)&K_s[(rg * 4 + 0) * KP + cf * 4] = w;                 \
                w.x = cvtpk(nx[it][1].x, nx[it][1].y);                         \
                w.y = cvtpk(nx[it][1].z, nx[it][1].w);                         \
                *(uint2*)&K_s[(rg * 4 + 1) * KP + cf * 4] = w;                 \
                w.x = cvtpk(nx[it][2].x, nx[it][2].y);                         \
                w.y = cvtpk(nx[it][2].z, nx[it][2].w);                         \
                *(uint2*)&K_s[(rg * 4 + 2) * KP + cf * 4] = w;                 \
                w.x = cvtpk(nx[it][3].x, nx[it][3].y);                         \
                w.y = cvtpk(nx[it][3].z, nx[it][3].w);                         \
                *(uint2*)&K_s[(rg * 4 + 3) * KP + cf * 4] = w;                 \
                if (cf < 128) {                                                \
                    const int v0 = cf * 4;                                     \
                    w.x = cvtpk(nx[it][0].x, nx[it][1].x);                     \
                    w.y = cvtpk(nx[it][2].x, nx[it][3].x);                     \
                    *(uint2*)&V_s[(v0 + 0) * VP + rg * 4] = w;                 \
                    w.x = cvtpk(nx[it][0].y, nx[it][1].y);                     \
                    w.y = cvtpk(nx[it][2].y, nx[it][3].y);                     \
                    *(uint2*)&V_s[(v0 + 1) * VP + rg * 4] = w;                 \
                    w.x = cvtpk(nx[it][0].z, nx[it][1].z);                     \
                    w.y = cvtpk(nx[it][2].z, nx[it][3].z);                     \
                    *(uint2*)&V_s[(v0 + 2) * VP + rg * 4] = w;                 \
                    w.x = cvtpk(nx[it][0].w, nx[it][1].w);                     \
                    w.y = cvtpk(nx[it][2].w, nx[it][3].w);                     \
                    *(uint2*)&V_s[(v0 + 3) * VP + rg * 4] = w;                 \
                }                                                              \
            }                                                                  \
        }                                                                      \
    }

    // ---- Q A-frags: lane holds Q[h=lr][kc*32 + g*8 + j], scale folded ----
    FragAB qf[18];
    {
        const float* qrow = qg + ((size_t)b * NH + lr) * D + g * 8;
        #pragma unroll
        for (int kc = 0; kc < 18; ++kc) {
            float4 x = *(const float4*)(qrow + kc * 32);
            float4 y = *(const float4*)(qrow + kc * 32 + 4);
            qf[kc].u[0] = cvtpk(x.x * SCALE_LOG2E, x.y * SCALE_LOG2E);
            qf[kc].u[1] = cvtpk(x.z * SCALE_LOG2E, x.w * SCALE_LOG2E);
            qf[kc].u[2] = cvtpk(y.x * SCALE_LOG2E, y.y * SCALE_LOG2E);
            qf[kc].u[3] = cvtpk(y.z * SCALE_LOG2E, y.w * SCALE_LOG2E);
        }
    }

    f32x4 acc[8];
    #pragma unroll
    for (int i = 0; i < 8; ++i) acc[i] = (f32x4){0.f, 0.f, 0.f, 0.f};
    float m2[4] = {NEGINF, NEGINF, NEGINF, NEGINF};
    float ll[4] = {0.f, 0.f, 0.f, 0.f};

    // ---- prologue: stage tile 0 (load -> write -> barrier) ----
    STAGE_LOAD(start);
    STAGE_WRITE();
    __syncthreads();

    for (int r0 = start; r0 < end; r0 += 32) {
        const bool have_next = (r0 + 32 < end);     // block-uniform
        if (have_next) STAGE_LOAD(r0 + 32);         // issue only; no waits

        // ---- scores: S[16h, 32r], two 16x16 tiles ----
        f32x4 sc0 = (f32x4){0.f, 0.f, 0.f, 0.f};
        f32x4 sc1 = (f32x4){0.f, 0.f, 0.f, 0.f};
        __builtin_amdgcn_s_setprio(1);
        #pragma unroll
        for (int kc = 0; kc < 18; ++kc) {
            FragAB kb0, kb1;
            kb0.v = *(const bf16x8*)&K_s[lr * KP + kc * 32 + g * 8];
            kb1.v = *(const bf16x8*)&K_s[(16 + lr) * KP + kc * 32 + g * 8];
            sc0 = __builtin_amdgcn_mfma_f32_16x16x32_bf16(qf[kc].v, kb0.v, sc0, 0, 0, 0);
            sc1 = __builtin_amdgcn_mfma_f32_16x16x32_bf16(qf[kc].v, kb1.v, sc1, 0, 0, 0);
        }
        __builtin_amdgcn_s_setprio(0);
        // mask invalid rows (lane's D-col = row r0+lr / r0+16+lr)
        if (r0 + lr >= end)      sc0 = (f32x4){NEGINF, NEGINF, NEGINF, NEGINF};
        if (r0 + 16 + lr >= end) sc1 = (f32x4){NEGINF, NEGINF, NEGINF, NEGINF};

        // ---- online softmax, 4 head-channels per lane (log2 domain) ----
        float p0[4], p1[4], scl[4];
        #pragma unroll
        for (int i = 0; i < 4; ++i) {
            float mt = fmaxf(sc0[i], sc1[i]);
            mt = fmaxf(mt, __shfl_xor(mt, 1));
            mt = fmaxf(mt, __shfl_xor(mt, 2));
            mt = fmaxf(mt, __shfl_xor(mt, 4));
            mt = fmaxf(mt, __shfl_xor(mt, 8));
            const float nm = fmaxf(m2[i], mt);
            scl[i] = exp2f(m2[i] - nm);
            p0[i] = exp2f(sc0[i] - nm);
            p1[i] = exp2f(sc1[i] - nm);
            float rs = p0[i] + p1[i];
            rs += __shfl_xor(rs, 1);
            rs += __shfl_xor(rs, 2);
            rs += __shfl_xor(rs, 4);
            rs += __shfl_xor(rs, 8);
            ll[i] = ll[i] * scl[i] + rs;
            m2[i] = nm;
        }

        // ---- P -> bf16, per-wave LDS transpose, re-read as PV A-frag ----
        short* pw = &P_s[wave * 16 * PP];
        #pragma unroll
        for (int i = 0; i < 4; ++i) {
            pw[(4 * g + i) * PP + lr]      = (short)cvtpk(p0[i], p0[i]);
            pw[(4 * g + i) * PP + 16 + lr] = (short)cvtpk(p1[i], p1[i]);
        }
        asm volatile("s_waitcnt lgkmcnt(0)" ::: "memory");  // cross-lane RAW
        FragAB pa;
        pa.v = *(const bf16x8*)&pw[lr * PP + g * 8];

        // ---- PV: wave's 128 v-cols, 8 mfma; rescale acc per head-chan ----
        const f32x4 scl4 = (f32x4){scl[0], scl[1], scl[2], scl[3]};
        __builtin_amdgcn_s_setprio(1);
        #pragma unroll
        for (int vt = 0; vt < 8; ++vt) {
            const int v = wave * 128 + vt * 16 + lr;
            FragAB vb;
            *(uint2*)&vb.u[0] = *(const uint2*)&V_s[v * VP + g * 8];
            *(uint2*)&vb.u[2] = *(const uint2*)&V_s[v * VP + g * 8 + 4];
            acc[vt] = acc[vt] * scl4;
            acc[vt] = __builtin_amdgcn_mfma_f32_16x16x32_bf16(pa.v, vb.v, acc[vt], 0, 0, 0);
        }
        __builtin_amdgcn_s_setprio(0);

        __syncthreads();                      // all waves done reading LDS
        if (have_next) STAGE_WRITE();         // waits on nx loads, writes LDS
        __syncthreads();                      // next round staged
    }

    // ---- write partials: lane covers h = 4g+i, v = wave*128 + vt*16 + lr --
    float* ob = ws_o + (((size_t)b * nchunk + c) * NH) * DV;
    #pragma unroll
    for (int vt = 0; vt < 8; ++vt) {
        const int v = wave * 128 + vt * 16 + lr;
        #pragma unroll
        for (int i = 0; i < 4; ++i)
            ob[(4 * g + i) * DV + v] = acc[vt][i];
    }
    if (wave == 0 && lr == 0) {
        float* mlb = ws_ml + ((size_t)b * nchunk + c) * NH * 2;
        #pragma unroll
        for (int i = 0; i < 4; ++i) {
            mlb[(4 * g + i) * 2]     = m2[i];   // log2-domain running max
            mlb[(4 * g + i) * 2 + 1] = ll[i];
        }
    }
#undef STAGE_LOAD
#undef STAGE_WRITE
}

__global__ __launch_bounds__(256)
void mla_reduce(const int* __restrict__ lens,
                const float* __restrict__ ws_o,
                const float* __restrict__ ws_ml,
                float* __restrict__ out,
                int nchunk, int chunk)
{
    const int h = blockIdx.x;
    const int b = blockIdx.y;
    const int tid = (int)threadIdx.x;
    const int total = lens[b] + 1;
    const int nact = min(nchunk, (total + chunk - 1) / chunk);

    float M = NEGINF;
    {
        int c = 0;
        for (; c + 4 <= nact; c += 4) {       // 4 independent loads in flight
            const float m0 = ws_ml[(((size_t)b * nchunk + c    ) * NH + h) * 2];
            const float m1 = ws_ml[(((size_t)b * nchunk + c + 1) * NH + h) * 2];
            const float m2_ = ws_ml[(((size_t)b * nchunk + c + 2) * NH + h) * 2];
            const float m3 = ws_ml[(((size_t)b * nchunk + c + 3) * NH + h) * 2];
            M = fmaxf(M, fmaxf(fmaxf(m0, m1), fmaxf(m2_, m3)));
        }
        for (; c < nact; ++c)
            M = fmaxf(M, ws_ml[(((size_t)b * nchunk + c) * NH + h) * 2]);
    }

    float a0 = 0.f, a1 = 0.f, L = 0.f;
    {
        int c = 0;
        for (; c + 2 <= nact; c += 2) {       // 2 independent iterations
            const size_t mlb0 = (((size_t)b * nchunk + c    ) * NH + h) * 2;
            const size_t mlb1 = (((size_t)b * nchunk + c + 1) * NH + h) * 2;
            const float w0 = exp2f(ws_ml[mlb0] - M);
            const float w1 = exp2f(ws_ml[mlb1] - M);
            const float2 o0 = *(const float2*)&ws_o[
                (((size_t)b * nchunk + c    ) * NH + h) * (size_t)DV + 2 * tid];
            const float2 o1 = *(const float2*)&ws_o[
                (((size_t)b * nchunk + c + 1) * NH + h) * (size_t)DV + 2 * tid];
            L += w0 * ws_ml[mlb0 + 1] + w1 * ws_ml[mlb1 + 1];
            a0 = fmaf(w1, o1.x, fmaf(w0, o0.x, a0));
            a1 = fmaf(w1, o1.y, fmaf(w0, o0.y, a1));
        }
        for (; c < nact; ++c) {
            const size_t mlb = (((size_t)b * nchunk + c) * NH + h) * 2;
            const float w = exp2f(ws_ml[mlb] - M);
            L += w * ws_ml[mlb + 1];
            const float2 o = *(const float2*)&ws_o[
                (((size_t)b * nchunk + c) * NH + h) * (size_t)DV + 2 * tid];
            a0 = fmaf(w, o.x, a0);
            a1 = fmaf(w, o.y, a1);
        }
    }
    const float inv = 1.f / L;
    *(float2*)&out[((size_t)b * NH + h) * (size_t)DV + 2 * tid] =
        make_float2(a0 * inv, a1 * inv);
}

extern "C" void kernel_launch(void* const* d_in, const int* in_sizes, int n_in,
                              void* d_out, int out_size, void* d_ws, size_t ws_size,
                              hipStream_t stream)
{
    (void)in_sizes; (void)n_in; (void)out_size;
    const float* qg    = (const float*)d_in[0];   // [B,H,576]
    const float* kvnew = (const float*)d_in[1];   // [B,1,576]
    const float* cache = (const float*)d_in[2];   // [B,4096,576]
    const int*   lens  = (const int*)d_in[3];     // [B]
    float* out = (float*)d_out;                   // [B,H,512] fp32

    // largest chunk split that fits the workspace (67 MB at nchunk=32)
    int nchunk = 32;
    while (nchunk > 1 &&
           (size_t)NB * nchunk * NH * (DV + 2) * sizeof(float) > ws_size)
        nchunk >>= 1;
    const int chunk = MAXLEN / nchunk;            // multiple of 32

    float* ws_o  = (float*)d_ws;
    float* ws_ml = ws_o + (size_t)NB * nchunk * NH * DV;

    dim3 gA(nchunk, NB);
    mla_mfma<<<gA, 256, 0, stream>>>(qg, kvnew, cache, lens, ws_o, ws_ml,
                                     nchunk, chunk);
    dim3 gB(NH, NB);
    mla_reduce<<<gB, 256, 0, stream>>>(lens, ws_o, ws_ml, out, nchunk, chunk);
}

// Round 14
// 138.458 us; speedup vs baseline: 1.4194x; 1.0378x over previous
//
#include <hip/hip_runtime.h>
#include <math.h>

// MLA decode attention, flash-decoding split + bf16 MFMA core.
// B=64, H=16, latent D=576, V=512, MAX_LEN=4096. fp32 in/out.
//
// R13 changes vs R12 (143.7us) — register-pressure relief + softmax trims:
//  1) Half-split prefetch: stage regs A (8 f4, issued before scores) +
//     B (12 f4, issued after PV just before the barrier, written right
//     after WRITE_A). Persistent in-flight regs 72->32; est VGPR ~250->~200
//     under the (256,2) cap, so the allocator stops serializing the
//     prefetch against its use (suspected reason R10's async gained only
//     13us).
//  2) l-reduction deferred to epilogue: ll is lane-local (saves 16
//     dependent shfl/round); valid because m2 trajectory is group-uniform.
//  3) Skip-rescale: wave-uniform __any(mt>m2) gates scl/exp2/acc-rescale;
//     groups that didn't grow get scl=1 (exact).
//  Kept: R10 skeleton (T14 async stage, dual-write K_s + Vt, 4-wave
//  redundant scores, log2 softmax, P_s transpose, PV 8 mfma/wave,
//  LDS 79360B -> 2 blocks/CU), OOB clamp, setprio, unrolled reduce.

typedef __attribute__((ext_vector_type(8))) short bf16x8;
typedef __attribute__((ext_vector_type(4))) float f32x4;

namespace {
constexpr int NB = 64, NH = 16, MAXLEN = 4096, D = 576, DV = 512;
constexpr int KP = 584;   // K_s row stride (bf16): 1168 B rows, 16B-aligned
constexpr int VP = 36;    // Vt row stride (bf16): 72 B rows, 8B-aligned
constexpr int PP = 40;    // P_s row stride (bf16)
constexpr float SCALE_LOG2E = 0.041666666666666664f * 1.4426950408889634f;
constexpr float NEGINF = -1e30f;
}

__device__ __forceinline__ uint32_t cvtpk(float a, float b) {
    uint32_t r;
    asm("v_cvt_pk_bf16_f32 %0, %1, %2" : "=v"(r) : "v"(a), "v"(b));
    return r;   // low16 = bf16(a), high16 = bf16(b)
}

union FragAB { bf16x8 v; uint32_t u[4]; };

__global__ __launch_bounds__(256, 2)
void mla_mfma(const float* __restrict__ qg, const float* __restrict__ kvnew,
              const float* __restrict__ cache, const int* __restrict__ lens,
              float* __restrict__ ws_o, float* __restrict__ ws_ml,
              int nchunk, int chunk)
{
    const int c = blockIdx.x, b = blockIdx.y;
    const int total = lens[b] + 1;
    const int start = c * chunk;
    if (start >= total) return;               // uniform, before any barrier
    const int end = min(start + chunk, total);
    const int newpos = total - 1;

    __shared__ short K_s[32 * KP];            // 37376 B row-major bf16
    __shared__ short V_s[DV * VP];            // 36864 B Vt[v][r] bf16
    __shared__ short P_s[4 * 16 * PP];        //  5120 B   (total 79360)

    const int tid  = (int)threadIdx.x;
    const int wave = tid >> 6, lane = tid & 63;
    const int lr = lane & 15, g = lane >> 4;

    const float* vnew = kvnew + (size_t)b * D;
    const float* cb   = cache + (size_t)b * MAXLEN * D;

    const int rg = tid >> 5;                  // staging row-group: rows rg*4+i
    const int cl = tid & 31;                  // staging col-lane

    float4 nxA[2][4];                         // early half (cols f4 0..63)
    float4 nxB[3][4];                         // late half (cols f4 64..143)

    // Per-it column index: cf = 32*it + cl. A = it{0,1}; B = it{2,3,4}.
    // Row index clamped to 4095 (branchless OOB); newpos row substituted.
#define ROWPTRS(R0N)                                                           \
        const int gr0 = (R0N) + rg * 4;                                        \
        const int r0c = min(gr0,     MAXLEN - 1);                              \
        const int r1c = min(gr0 + 1, MAXLEN - 1);                              \
        const int r2c = min(gr0 + 2, MAXLEN - 1);                              \
        const int r3c = min(gr0 + 3, MAXLEN - 1);                              \
        const float* s0 = (gr0     == newpos) ? vnew : (cb + (size_t)r0c * D); \
        const float* s1 = (gr0 + 1 == newpos) ? vnew : (cb + (size_t)r1c * D); \
        const float* s2 = (gr0 + 2 == newpos) ? vnew : (cb + (size_t)r2c * D); \
        const float* s3 = (gr0 + 3 == newpos) ? vnew : (cb + (size_t)r3c * D);

#define STAGE_LOAD_A(R0N)                                                      \
    {                                                                          \
        ROWPTRS(R0N)                                                           \
        _Pragma("unroll")                                                      \
        for (int it = 0; it < 2; ++it) {                                       \
            const int cf = 32 * it + cl;                                       \
            nxA[it][0] = *(const float4*)(s0 + cf * 4);                        \
            nxA[it][1] = *(const float4*)(s1 + cf * 4);                        \
            nxA[it][2] = *(const float4*)(s2 + cf * 4);                        \
            nxA[it][3] = *(const float4*)(s3 + cf * 4);                        \
        }                                                                      \
    }

#define STAGE_LOAD_B(R0N)                                                      \
    {                                                                          \
        ROWPTRS(R0N)                                                           \
        _Pragma("unroll")                                                      \
        for (int jt = 0; jt < 3; ++jt) {                                       \
            const int cf = 32 * (jt + 2) + cl;                                 \
            if (cf < 144) {                                                    \
                nxB[jt][0] = *(const float4*)(s0 + cf * 4);                    \
                nxB[jt][1] = *(const float4*)(s1 + cf * 4);                    \
                nxB[jt][2] = *(const float4*)(s2 + cf * 4);                    \
                nxB[jt][3] = *(const float4*)(s3 + cf * 4);                    \
            }                                                                  \
        }                                                                      \
    }

#define WRITE_ONE(NX, CF)                                                      \
    {                                                                          \
        uint2 w;                                                               \
        w.x = cvtpk(NX[0].x, NX[0].y); w.y = cvtpk(NX[0].z, NX[0].w);          \
        *(uint2*)&K_s[(rg * 4 + 0) * KP + (CF) * 4] = w;                       \
        w.x = cvtpk(NX[1].x, NX[1].y); w.y = cvtpk(NX[1].z, NX[1].w);          \
        *(uint2*)&K_s[(rg * 4 + 1) * KP + (CF) * 4] = w;                       \
        w.x = cvtpk(NX[2].x, NX[2].y); w.y = cvtpk(NX[2].z, NX[2].w);          \
        *(uint2*)&K_s[(rg * 4 + 2) * KP + (CF) * 4] = w;                       \
        w.x = cvtpk(NX[3].x, NX[3].y); w.y = cvtpk(NX[3].z, NX[3].w);          \
        *(uint2*)&K_s[(rg * 4 + 3) * KP + (CF) * 4] = w;                       \
        if ((CF) < 128) {                                                      \
            const int v0 = (CF) * 4;                                           \
            w.x = cvtpk(NX[0].x, NX[1].x); w.y = cvtpk(NX[2].x, NX[3].x);      \
            *(uint2*)&V_s[(v0 + 0) * VP + rg * 4] = w;                         \
            w.x = cvtpk(NX[0].y, NX[1].y); w.y = cvtpk(NX[2].y, NX[3].y);      \
            *(uint2*)&V_s[(v0 + 1) * VP + rg * 4] = w;                         \
            w.x = cvtpk(NX[0].z, NX[1].z); w.y = cvtpk(NX[2].z, NX[3].z);      \
            *(uint2*)&V_s[(v0 + 2) * VP + rg * 4] = w;                         \
            w.x = cvtpk(NX[0].w, NX[1].w); w.y = cvtpk(NX[2].w, NX[3].w);      \
            *(uint2*)&V_s[(v0 + 3) * VP + rg * 4] = w;                         \
        }                                                                      \
    }

#define STAGE_WRITE_A()                                                        \
    {                                                                          \
        _Pragma("unroll")                                                      \
        for (int it = 0; it < 2; ++it) {                                       \
            const int cf = 32 * it + cl;                                       \
            WRITE_ONE(nxA[it], cf)                                             \
        }                                                                      \
    }

#define STAGE_WRITE_B()                                                        \
    {                                                                          \
        _Pragma("unroll")                                                      \
        for (int jt = 0; jt < 3; ++jt) {                                       \
            const int cf = 32 * (jt + 2) + cl;                                 \
            if (cf < 144) { WRITE_ONE(nxB[jt], cf) }                           \
        }                                                                      \
    }

    // ---- Q A-frags: lane holds Q[h=lr][kc*32 + g*8 + j], scale folded ----
    FragAB qf[18];
    {
        const float* qrow = qg + ((size_t)b * NH + lr) * D + g * 8;
        #pragma unroll
        for (int kc = 0; kc < 18; ++kc) {
            float4 x = *(const float4*)(qrow + kc * 32);
            float4 y = *(const float4*)(qrow + kc * 32 + 4);
            qf[kc].u[0] = cvtpk(x.x * SCALE_LOG2E, x.y * SCALE_LOG2E);
            qf[kc].u[1] = cvtpk(x.z * SCALE_LOG2E, x.w * SCALE_LOG2E);
            qf[kc].u[2] = cvtpk(y.x * SCALE_LOG2E, y.y * SCALE_LOG2E);
            qf[kc].u[3] = cvtpk(y.z * SCALE_LOG2E, y.w * SCALE_LOG2E);
        }
    }

    f32x4 acc[8];
    #pragma unroll
    for (int i = 0; i < 8; ++i) acc[i] = (f32x4){0.f, 0.f, 0.f, 0.f};
    float m2[4] = {NEGINF, NEGINF, NEGINF, NEGINF};
    float ll[4] = {0.f, 0.f, 0.f, 0.f};      // LANE-LOCAL partial sums (R13)

    // ---- prologue: stage tile 0 ----
    STAGE_LOAD_A(start);
    STAGE_LOAD_B(start);
    STAGE_WRITE_A();
    STAGE_WRITE_B();
    __syncthreads();

    for (int r0 = start; r0 < end; r0 += 32) {
        const bool have_next = (r0 + 32 < end);     // block-uniform
        if (have_next) STAGE_LOAD_A(r0 + 32);       // early half in flight

        // ---- scores: S[16h, 32r], two 16x16 tiles ----
        f32x4 sc0 = (f32x4){0.f, 0.f, 0.f, 0.f};
        f32x4 sc1 = (f32x4){0.f, 0.f, 0.f, 0.f};
        __builtin_amdgcn_s_setprio(1);
        #pragma unroll
        for (int kc = 0; kc < 18; ++kc) {
            FragAB kb0, kb1;
            kb0.v = *(const bf16x8*)&K_s[lr * KP + kc * 32 + g * 8];
            kb1.v = *(const bf16x8*)&K_s[(16 + lr) * KP + kc * 32 + g * 8];
            sc0 = __builtin_amdgcn_mfma_f32_16x16x32_bf16(qf[kc].v, kb0.v, sc0, 0, 0, 0);
            sc1 = __builtin_amdgcn_mfma_f32_16x16x32_bf16(qf[kc].v, kb1.v, sc1, 0, 0, 0);
        }
        __builtin_amdgcn_s_setprio(0);
        // mask invalid rows (lane's D-col = row r0+lr / r0+16+lr)
        if (r0 + lr >= end)      sc0 = (f32x4){NEGINF, NEGINF, NEGINF, NEGINF};
        if (r0 + 16 + lr >= end) sc1 = (f32x4){NEGINF, NEGINF, NEGINF, NEGINF};

        // ---- online softmax (log2 domain), skip-rescale + deferred l ----
        float mt[4];
        int grew = 0;
        #pragma unroll
        for (int i = 0; i < 4; ++i) {
            float t = fmaxf(sc0[i], sc1[i]);
            t = fmaxf(t, __shfl_xor(t, 1));
            t = fmaxf(t, __shfl_xor(t, 2));
            t = fmaxf(t, __shfl_xor(t, 4));
            t = fmaxf(t, __shfl_xor(t, 8));
            mt[i] = t;
            grew |= (t > m2[i]) ? 1 : 0;
        }
        if (__any(grew)) {                   // wave-uniform branch
            float scl[4];
            #pragma unroll
            for (int i = 0; i < 4; ++i) {
                const float nm = fmaxf(m2[i], mt[i]);
                scl[i] = exp2f(m2[i] - nm);  // ==1 for non-growing groups
                m2[i] = nm;
                ll[i] *= scl[i];
            }
            const f32x4 scl4 = (f32x4){scl[0], scl[1], scl[2], scl[3]};
            #pragma unroll
            for (int vt = 0; vt < 8; ++vt) acc[vt] = acc[vt] * scl4;
        }
        float p0[4], p1[4];
        #pragma unroll
        for (int i = 0; i < 4; ++i) {
            p0[i] = exp2f(sc0[i] - m2[i]);
            p1[i] = exp2f(sc1[i] - m2[i]);
            ll[i] += p0[i] + p1[i];          // lane-local; reduced at epilogue
        }

        // ---- P -> bf16, per-wave LDS transpose, re-read as PV A-frag ----
        short* pw = &P_s[wave * 16 * PP];
        #pragma unroll
        for (int i = 0; i < 4; ++i) {
            pw[(4 * g + i) * PP + lr]      = (short)cvtpk(p0[i], p0[i]);
            pw[(4 * g + i) * PP + 16 + lr] = (short)cvtpk(p1[i], p1[i]);
        }
        asm volatile("s_waitcnt lgkmcnt(0)" ::: "memory");  // cross-lane RAW
        FragAB pa;
        pa.v = *(const bf16x8*)&pw[lr * PP + g * 8];

        // ---- PV: wave's 128 v-cols, 8 mfma ----
        __builtin_amdgcn_s_setprio(1);
        #pragma unroll
        for (int vt = 0; vt < 8; ++vt) {
            const int v = wave * 128 + vt * 16 + lr;
            FragAB vb;
            *(uint2*)&vb.u[0] = *(const uint2*)&V_s[v * VP + g * 8];
            *(uint2*)&vb.u[2] = *(const uint2*)&V_s[v * VP + g * 8 + 4];
            acc[vt] = __builtin_amdgcn_mfma_f32_16x16x32_bf16(pa.v, vb.v, acc[vt], 0, 0, 0);
        }
        __builtin_amdgcn_s_setprio(0);

        if (have_next) STAGE_LOAD_B(r0 + 32);   // late half issued pre-barrier
        __syncthreads();                        // all waves done reading LDS
        if (have_next) { STAGE_WRITE_A(); STAGE_WRITE_B(); }
        __syncthreads();                        // next round staged
    }

    // ---- epilogue: reduce lane-local l across the 16-lane dd-group ----
    #pragma unroll
    for (int i = 0; i < 4; ++i) {
        float s = ll[i];
        s += __shfl_xor(s, 1);
        s += __shfl_xor(s, 2);
        s += __shfl_xor(s, 4);
        s += __shfl_xor(s, 8);
        ll[i] = s;
    }

    // ---- write partials: lane covers h = 4g+i, v = wave*128 + vt*16 + lr --
    float* ob = ws_o + (((size_t)b * nchunk + c) * NH) * DV;
    #pragma unroll
    for (int vt = 0; vt < 8; ++vt) {
        const int v = wave * 128 + vt * 16 + lr;
        #pragma unroll
        for (int i = 0; i < 4; ++i)
            ob[(4 * g + i) * DV + v] = acc[vt][i];
    }
    if (wave == 0 && lr == 0) {
        float* mlb = ws_ml + ((size_t)b * nchunk + c) * NH * 2;
        #pragma unroll
        for (int i = 0; i < 4; ++i) {
            mlb[(4 * g + i) * 2]     = m2[i];   // log2-domain running max
            mlb[(4 * g + i) * 2 + 1] = ll[i];
        }
    }
#undef STAGE_LOAD_A
#undef STAGE_LOAD_B
#undef STAGE_WRITE_A
#undef STAGE_WRITE_B
#undef WRITE_ONE
#undef ROWPTRS
}

__global__ __launch_bounds__(256)
void mla_reduce(const int* __restrict__ lens,
                const float* __restrict__ ws_o,
                const float* __restrict__ ws_ml,
                float* __restrict__ out,
                int nchunk, int chunk)
{
    const int h = blockIdx.x;
    const int b = blockIdx.y;
    const int tid = (int)threadIdx.x;
    const int total = lens[b] + 1;
    const int nact = min(nchunk, (total + chunk - 1) / chunk);

    float M = NEGINF;
    {
        int c = 0;
        for (; c + 4 <= nact; c += 4) {       // 4 independent loads in flight
            const float m0 = ws_ml[(((size_t)b * nchunk + c    ) * NH + h) * 2];
            const float m1 = ws_ml[(((size_t)b * nchunk + c + 1) * NH + h) * 2];
            const float m2_ = ws_ml[(((size_t)b * nchunk + c + 2) * NH + h) * 2];
            const float m3 = ws_ml[(((size_t)b * nchunk + c + 3) * NH + h) * 2];
            M = fmaxf(M, fmaxf(fmaxf(m0, m1), fmaxf(m2_, m3)));
        }
        for (; c < nact; ++c)
            M = fmaxf(M, ws_ml[(((size_t)b * nchunk + c) * NH + h) * 2]);
    }

    float a0 = 0.f, a1 = 0.f, L = 0.f;
    {
        int c = 0;
        for (; c + 2 <= nact; c += 2) {       // 2 independent iterations
            const size_t mlb0 = (((size_t)b * nchunk + c    ) * NH + h) * 2;
            const size_t mlb1 = (((size_t)b * nchunk + c + 1) * NH + h) * 2;
            const float w0 = exp2f(ws_ml[mlb0] - M);
            const float w1 = exp2f(ws_ml[mlb1] - M);
            const float2 o0 = *(const float2*)&ws_o[
                (((size_t)b * nchunk + c    ) * NH + h) * (size_t)DV + 2 * tid];
            const float2 o1 = *(const float2*)&ws_o[
                (((size_t)b * nchunk + c + 1) * NH + h) * (size_t)DV + 2 * tid];
            L += w0 * ws_ml[mlb0 + 1] + w1 * ws_ml[mlb1 + 1];
            a0 = fmaf(w1, o1.x, fmaf(w0, o0.x, a0));
            a1 = fmaf(w1, o1.y, fmaf(w0, o0.y, a1));
        }
        for (; c < nact; ++c) {
            const size_t mlb = (((size_t)b * nchunk + c) * NH + h) * 2;
            const float w = exp2f(ws_ml[mlb] - M);
            L += w * ws_ml[mlb + 1];
            const float2 o = *(const float2*)&ws_o[
                (((size_t)b * nchunk + c) * NH + h) * (size_t)DV + 2 * tid];
            a0 = fmaf(w, o.x, a0);
            a1 = fmaf(w, o.y, a1);
        }
    }
    const float inv = 1.f / L;
    *(float2*)&out[((size_t)b * NH + h) * (size_t)DV + 2 * tid] =
        make_float2(a0 * inv, a1 * inv);
}

extern "C" void kernel_launch(void* const* d_in, const int* in_sizes, int n_in,
                              void* d_out, int out_size, void* d_ws, size_t ws_size,
                              hipStream_t stream)
{
    (void)in_sizes; (void)n_in; (void)out_size;
    const float* qg    = (const float*)d_in[0];   // [B,H,576]
    const float* kvnew = (const float*)d_in[1];   // [B,1,576]
    const float* cache = (const float*)d_in[2];   // [B,4096,576]
    const int*   lens  = (const int*)d_in[3];     // [B]
    float* out = (float*)d_out;                   // [B,H,512] fp32

    // largest chunk split that fits the workspace (67 MB at nchunk=32)
    int nchunk = 32;
    while (nchunk > 1 &&
           (size_t)NB * nchunk * NH * (DV + 2) * sizeof(float) > ws_size)
        nchunk >>= 1;
    const int chunk = MAXLEN / nchunk;            // multiple of 32

    float* ws_o  = (float*)d_ws;
    float* ws_ml = ws_o + (size_t)NB * nchunk * NH * DV;

    dim3 gA(nchunk, NB);
    mla_mfma<<<gA, 256, 0, stream>>>(qg, kvnew, cache, lens, ws_o, ws_ml,
                                     nchunk, chunk);
    dim3 gB(NH, NB);
    mla_reduce<<<gB, 256, 0, stream>>>(lens, ws_o, ws_ml, out, nchunk, chunk);
}